// Round 7
// baseline (1185.501 us; speedup 1.0000x reference)
//
#include <hip/hip_runtime.h>

#define N_NODES 50000
#define N_EDGES 800000
#define F_INP   32
#define HDIM    64
#define EDIM    16
#define COUT    40
#define NGRAPH  64

// ---------------------------------------------------------------- sort by dst
__global__ void hist_kernel(const int* __restrict__ dst, int* __restrict__ cnt, int E) {
    int e = blockIdx.x * 256 + threadIdx.x;
    if (e < E) atomicAdd(&cnt[dst[e]], 1);
}

__global__ void scan_part_kernel(const int* __restrict__ cnt, int* __restrict__ bsum, int n) {
    __shared__ int red[256];
    int tid = threadIdx.x;
    int idx = blockIdx.x * 256 + tid;
    red[tid] = (idx < n) ? cnt[idx] : 0;
    __syncthreads();
    for (int off = 128; off > 0; off >>= 1) {
        if (tid < off) red[tid] += red[tid + off];
        __syncthreads();
    }
    if (tid == 0) bsum[blockIdx.x] = red[0];
}

__global__ void scan_top_kernel(int* __restrict__ bsum, int nb) {
    __shared__ int tmp[256];
    int tid = threadIdx.x;
    int v = (tid < nb) ? bsum[tid] : 0;
    tmp[tid] = v;
    __syncthreads();
    for (int off = 1; off < 256; off <<= 1) {
        int x = (tid >= off) ? tmp[tid - off] : 0;
        __syncthreads();
        tmp[tid] += x;
        __syncthreads();
    }
    if (tid < nb) bsum[tid] = tmp[tid] - v;   // exclusive
}

__global__ void scan_apply_kernel(const int* __restrict__ cnt, const int* __restrict__ bsum,
                                  int* __restrict__ offsets, int* __restrict__ cursor, int n) {
    __shared__ int tmp[256];
    int tid = threadIdx.x;
    int idx = blockIdx.x * 256 + tid;
    int v = (idx < n) ? cnt[idx] : 0;
    tmp[tid] = v;
    __syncthreads();
    for (int off = 1; off < 256; off <<= 1) {
        int x = (tid >= off) ? tmp[tid - off] : 0;
        __syncthreads();
        tmp[tid] += x;
        __syncthreads();
    }
    int excl = tmp[tid] - v + bsum[blockIdx.x];
    if (idx < n) { offsets[idx] = excl; cursor[idx] = excl; }
    if (idx == n - 1) offsets[n] = excl + v;
}

// records pos[e] (final slot of edge e) and sorted[p] (fallback path)
__global__ void scatter_kernel(const int* __restrict__ dst, int* __restrict__ cursor,
                               int* __restrict__ pos, int* __restrict__ sorted, int E) {
    int e = blockIdx.x * 256 + threadIdx.x;
    if (e < E) {
        int p = atomicAdd(&cursor[dst[e]], 1);
        pos[e] = p;
        sorted[p] = e;
    }
}

// coalesced-read / scattered-write permute: thread e reads its own edge
// (sequential) and fire-and-forget writes to slot pos[e].
__global__ void permute_kernel(const int* __restrict__ pos, const int* __restrict__ src,
                               const float4* __restrict__ ea, float4* __restrict__ ea_s,
                               int* __restrict__ src_s, int E) {
    int e = blockIdx.x * 256 + threadIdx.x;
    if (e >= E) return;
    int p = pos[e];
    float4 a0 = ea[e * 4 + 0], a1 = ea[e * 4 + 1];
    float4 a2 = ea[e * 4 + 2], a3 = ea[e * 4 + 3];
    ea_s[p * 4 + 0] = a0; ea_s[p * 4 + 1] = a1;
    ea_s[p * 4 + 2] = a2; ea_s[p * 4 + 3] = a3;
    src_s[p] = src[e];
}

// batch is sorted ascending; find graph start offsets
__global__ void gstart_kernel(const int* __restrict__ batch, int* __restrict__ gstart,
                              int N, int G) {
    int n = blockIdx.x * 256 + threadIdx.x;
    if (n >= N) return;
    int g  = batch[n];
    int gp = (n == 0) ? -1 : batch[n - 1];
    for (int gg = gp + 1; gg <= g; gg++) gstart[gg] = n;
    if (n == N - 1) {
        for (int gg = g + 1; gg <= G; gg++) gstart[gg] = N;
    }
}

// ---------------------------------------------------------------- input linear
__global__ void lin_in_kernel(const float* __restrict__ x, const float* __restrict__ W,
                              const float* __restrict__ b, float* __restrict__ h,
                              float* __restrict__ nstats, int N) {
    __shared__ float red[256];
    int tid = threadIdx.x;
    int c = tid & 63;
    float w[F_INP];
#pragma unroll
    for (int k = 0; k < F_INP; k++) w[k] = W[k * HDIM + c];
    float bc = b[c];
    float s = 0.f, ss = 0.f;
    for (int node = blockIdx.x * 4 + (tid >> 6); node < N; node += gridDim.x * 4) {
        const float4* xr = (const float4*)(x + (size_t)node * F_INP);
        float acc = bc;
#pragma unroll
        for (int k4 = 0; k4 < F_INP / 4; k4++) {
            float4 xv = xr[k4];
            acc += xv.x * w[4 * k4] + xv.y * w[4 * k4 + 1]
                 + xv.z * w[4 * k4 + 2] + xv.w * w[4 * k4 + 3];
        }
        h[(size_t)node * HDIM + c] = acc;
        s += acc; ss += acc * acc;
    }
    __syncthreads();
    red[tid] = s;
    __syncthreads();
    if (tid < 64) atomicAdd(&nstats[tid], red[tid] + red[tid + 64] + red[tid + 128] + red[tid + 192]);
    __syncthreads();
    red[tid] = ss;
    __syncthreads();
    if (tid < 64) atomicAdd(&nstats[64 + tid], red[tid] + red[tid + 64] + red[tid + 128] + red[tid + 192]);
}

// ---------------------------------------------------------------- aggregation
// one wave per node (lane = channel). BN+ReLU fused (z = hv*A + B).
// Fast path: 4-deep register pipeline on the random h[src] gather; int32
// pre-shifted offsets (src<<6) shfl-broadcast; sequential ea reads.
// No seg_max: m in [1e-7,~8], exp cannot overflow; softmax shift-invariant.
__global__ void agg_kernel(const float* __restrict__ h, const int* __restrict__ srcarr,
                           const float* __restrict__ ea, const float* __restrict__ We,
                           const float* __restrict__ be, const float* __restrict__ tptr,
                           const float* __restrict__ stats,
                           const float* __restrict__ gamma, const float* __restrict__ beta,
                           const int* __restrict__ offsets, const int* __restrict__ sorted,
                           float* __restrict__ out, int N) {
    int tid = threadIdx.x;
    int c = tid & 63;
    float inv = 1.0f / (float)N;
    float mu  = stats[c] * inv;
    float var = stats[HDIM + c] * inv - mu * mu;
    float rs  = rsqrtf(var + 1e-5f);
    float A   = rs * gamma[c];
    float B   = beta[c] - mu * A;
    float w[EDIM];
#pragma unroll
    for (int k = 0; k < EDIM; k++) w[k] = We[k * HDIM + c];
    float bc = be[c];
    float tval = *tptr;
    int node = blockIdx.x * 4 + (tid >> 6);
    if (node >= N) return;
    int beg = offsets[node], end = offsets[node + 1];
    float denom = 0.f, num = 0.f;
    if (sorted == nullptr) {
        for (int cb = beg; cb < end; cb += 64) {
            int nc = end - cb; if (nc > 64) nc = 64;
            int s_l = (c < nc) ? (srcarr[cb + c] << 6) : 0;   // pre-scaled row offset
            float hc[4];
#pragma unroll
            for (int p = 0; p < 4; p++) {
                int jp = (p < nc) ? p : nc - 1;
                hc[p] = h[__shfl(s_l, jp) + c];
            }
            const float4* ar = (const float4*)(ea + (size_t)cb * EDIM);
            for (int j = 0; j < nc; j += 4) {
                float hn[4];
#pragma unroll
                for (int u = 0; u < 4; u++) {
                    int jn = j + 4 + u;
                    hn[u] = (jn < nc) ? h[__shfl(s_l, jn) + c] : 0.f;
                }
#pragma unroll
                for (int u = 0; u < 4; u++) {
                    if (j + u < nc) {
                        float4 a0 = ar[4 * u + 0], a1 = ar[4 * u + 1];
                        float4 a2 = ar[4 * u + 2], a3 = ar[4 * u + 3];
                        float acc = bc
                            + a0.x * w[0]  + a0.y * w[1]  + a0.z * w[2]  + a0.w * w[3]
                            + a1.x * w[4]  + a1.y * w[5]  + a1.z * w[6]  + a1.w * w[7]
                            + a2.x * w[8]  + a2.y * w[9]  + a2.z * w[10] + a2.w * w[11]
                            + a3.x * w[12] + a3.y * w[13] + a3.z * w[14] + a3.w * w[15];
                        float zv = fmaxf(hc[u] * A + B, 0.f);
                        float m  = fmaxf(zv + acc, 0.f) + 1e-7f;
                        float ex = __expf(m * tval);
                        denom += ex;
                        num   += ex * m;
                    }
                }
                ar += 16;
                hc[0] = hn[0]; hc[1] = hn[1]; hc[2] = hn[2]; hc[3] = hn[3];
            }
        }
    } else {
        for (int cb = beg; cb < end; cb += 64) {
            int nc = end - cb; if (nc > 64) nc = 64;
            int e_l = 0, s_l = 0;
            if (c < nc) { e_l = sorted[cb + c]; s_l = srcarr[e_l]; }
            for (int j = 0; j < nc; j++) {
                int e = __shfl(e_l, j);
                int s = __shfl(s_l, j);
                const float4* ar = (const float4*)(ea + (size_t)e * EDIM);
                float4 a0 = ar[0], a1 = ar[1], a2 = ar[2], a3 = ar[3];
                float acc = bc
                    + a0.x * w[0]  + a0.y * w[1]  + a0.z * w[2]  + a0.w * w[3]
                    + a1.x * w[4]  + a1.y * w[5]  + a1.z * w[6]  + a1.w * w[7]
                    + a2.x * w[8]  + a2.y * w[9]  + a2.z * w[10] + a2.w * w[11]
                    + a3.x * w[12] + a3.y * w[13] + a3.z * w[14] + a3.w * w[15];
                float hv = h[(size_t)s * HDIM + c];
                float zv = fmaxf(hv * A + B, 0.f);
                float m  = fmaxf(zv + acc, 0.f) + 1e-7f;
                float ex = __expf(m * tval);
                denom += ex;
                num   += ex * m;
            }
        }
    }
    float hv = h[(size_t)node * HDIM + c];
    float zn = fmaxf(hv * A + B, 0.f);
    out[(size_t)node * HDIM + c] = num / (denom + 1e-16f) + zn;
}

// ---------------------------------------------------------------- MLP part 1
// h1 = in @ W1 + b1  (N,64)@(64,128); grid == exact tile count (no tail
// imbalance); float4 LDS reads; epilogue: h1 stats
__global__ __launch_bounds__(256, 3) void mlp1_kernel(
        const float* __restrict__ in, const float* __restrict__ W1,
        const float* __restrict__ b1, float* __restrict__ h1,
        float* __restrict__ stats, int N) {
    __shared__ float sW[HDIM * 128];         // 32 KB
    __shared__ float srow[32 * 68];          // 8.5 KB
    __shared__ float red[256];
    int tid = threadIdx.x;
    for (int i = tid; i < HDIM * 128 / 4; i += 256)
        ((float4*)sW)[i] = ((const float4*)W1)[i];
    int tx = tid & 31, ty = tid >> 5;
    float4 bv = *(const float4*)&b1[4 * tx];
    float s0 = 0, s1 = 0, s2 = 0, s3 = 0, q0 = 0, q1 = 0, q2 = 0, q3 = 0;
    int base = blockIdx.x << 5;
    {
        for (int i = tid; i < 32 * 16; i += 256) {
            int r = i >> 4, q = i & 15;
            int node = base + r;
            float4 v = make_float4(0.f, 0.f, 0.f, 0.f);
            if (node < N) v = *(const float4*)&in[(size_t)node * HDIM + 4 * q];
            *(float4*)&srow[r * 68 + 4 * q] = v;
        }
        __syncthreads();
        float acc[4][4];
#pragma unroll
        for (int j = 0; j < 4; j++) { acc[j][0] = bv.x; acc[j][1] = bv.y; acc[j][2] = bv.z; acc[j][3] = bv.w; }
#pragma unroll 4
        for (int k4 = 0; k4 < 16; k4++) {
            float4 rv0 = *(const float4*)&srow[(ty * 4 + 0) * 68 + 4 * k4];
            float4 rv1 = *(const float4*)&srow[(ty * 4 + 1) * 68 + 4 * k4];
            float4 rv2 = *(const float4*)&srow[(ty * 4 + 2) * 68 + 4 * k4];
            float4 rv3 = *(const float4*)&srow[(ty * 4 + 3) * 68 + 4 * k4];
#pragma unroll
            for (int kk = 0; kk < 4; kk++) {
                float4 wv = *(const float4*)&sW[(4 * k4 + kk) * 128 + 4 * tx];
                float f0 = ((const float*)&rv0)[kk];
                float f1 = ((const float*)&rv1)[kk];
                float f2 = ((const float*)&rv2)[kk];
                float f3 = ((const float*)&rv3)[kk];
                acc[0][0] += f0 * wv.x; acc[0][1] += f0 * wv.y; acc[0][2] += f0 * wv.z; acc[0][3] += f0 * wv.w;
                acc[1][0] += f1 * wv.x; acc[1][1] += f1 * wv.y; acc[1][2] += f1 * wv.z; acc[1][3] += f1 * wv.w;
                acc[2][0] += f2 * wv.x; acc[2][1] += f2 * wv.y; acc[2][2] += f2 * wv.z; acc[2][3] += f2 * wv.w;
                acc[3][0] += f3 * wv.x; acc[3][1] += f3 * wv.y; acc[3][2] += f3 * wv.z; acc[3][3] += f3 * wv.w;
            }
        }
#pragma unroll
        for (int j = 0; j < 4; j++) {
            int node = base + ty * 4 + j;
            if (node < N) {
                *(float4*)&h1[(size_t)node * 128 + 4 * tx] =
                    make_float4(acc[j][0], acc[j][1], acc[j][2], acc[j][3]);
                s0 += acc[j][0]; q0 += acc[j][0] * acc[j][0];
                s1 += acc[j][1]; q1 += acc[j][1] * acc[j][1];
                s2 += acc[j][2]; q2 += acc[j][2] * acc[j][2];
                s3 += acc[j][3]; q3 += acc[j][3] * acc[j][3];
            }
        }
    }
    float sq[8] = { s0, s1, s2, s3, q0, q1, q2, q3 };
#pragma unroll
    for (int q = 0; q < 8; q++) {
        __syncthreads();
        red[tid] = sq[q];
        __syncthreads();
        if (tid < 32) {
            float t = 0.f;
#pragma unroll
            for (int k = 0; k < 8; k++) t += red[tid + 32 * k];
            atomicAdd(&stats[(q < 4 ? 0 : 128) + 4 * tid + (q & 3)], t);
        }
    }
}

// ---------------------------------------------------------------- MLP part 2
// h += relu(BN(h1)) @ W2 + b2; grid == exact tiles; epilogue: stats of NEW h
__global__ __launch_bounds__(256, 3) void mlp2_kernel(
        const float* __restrict__ h1, const float* __restrict__ stats,
        const float* __restrict__ mg, const float* __restrict__ mb,
        const float* __restrict__ W2, const float* __restrict__ b2,
        float* __restrict__ h, float* __restrict__ nstats, int N) {
    __shared__ float sW[128 * HDIM];         // 32 KB
    __shared__ float sact[32 * 132];         // 16.5 KB
    __shared__ float sbn[512];
    __shared__ float red[256];
    int tid = threadIdx.x;
    for (int i = tid; i < 128 * HDIM / 4; i += 256)
        ((float4*)sW)[i] = ((const float4*)W2)[i];
    if (tid < 128) {
        float inv = 1.0f / (float)N;
        float mu  = stats[tid] * inv;
        float var = stats[128 + tid] * inv - mu * mu;
        sbn[tid]       = mu;
        sbn[128 + tid] = rsqrtf(var + 1e-5f);
        sbn[256 + tid] = mg[tid];
        sbn[384 + tid] = mb[tid];
    }
    int tx = tid & 15, ty = tid >> 4;
    float4 bv = *(const float4*)&b2[4 * tx];
    float s0 = 0, s1 = 0, s2 = 0, s3 = 0, q0 = 0, q1 = 0, q2 = 0, q3 = 0;
    int base = blockIdx.x << 5;
    {
        __syncthreads();
        for (int i = tid; i < 32 * 32; i += 256) {
            int r = i >> 5, q = i & 31;
            int node = base + r;
            float4 v = make_float4(0.f, 0.f, 0.f, 0.f);
            if (node < N) {
                v = *(const float4*)&h1[(size_t)node * 128 + 4 * q];
                int o = 4 * q;
                v.x = fmaxf((v.x - sbn[o + 0]) * sbn[128 + o + 0] * sbn[256 + o + 0] + sbn[384 + o + 0], 0.f);
                v.y = fmaxf((v.y - sbn[o + 1]) * sbn[128 + o + 1] * sbn[256 + o + 1] + sbn[384 + o + 1], 0.f);
                v.z = fmaxf((v.z - sbn[o + 2]) * sbn[128 + o + 2] * sbn[256 + o + 2] + sbn[384 + o + 2], 0.f);
                v.w = fmaxf((v.w - sbn[o + 3]) * sbn[128 + o + 3] * sbn[256 + o + 3] + sbn[384 + o + 3], 0.f);
            }
            *(float4*)&sact[r * 132 + 4 * q] = v;
        }
        __syncthreads();
        float acc[2][4];
#pragma unroll
        for (int j = 0; j < 2; j++) { acc[j][0] = bv.x; acc[j][1] = bv.y; acc[j][2] = bv.z; acc[j][3] = bv.w; }
#pragma unroll 4
        for (int k4 = 0; k4 < 32; k4++) {
            float4 rv0 = *(const float4*)&sact[(ty * 2 + 0) * 132 + 4 * k4];
            float4 rv1 = *(const float4*)&sact[(ty * 2 + 1) * 132 + 4 * k4];
#pragma unroll
            for (int kk = 0; kk < 4; kk++) {
                float4 wv = *(const float4*)&sW[(4 * k4 + kk) * HDIM + 4 * tx];
                float f0 = ((const float*)&rv0)[kk];
                float f1 = ((const float*)&rv1)[kk];
                acc[0][0] += f0 * wv.x; acc[0][1] += f0 * wv.y; acc[0][2] += f0 * wv.z; acc[0][3] += f0 * wv.w;
                acc[1][0] += f1 * wv.x; acc[1][1] += f1 * wv.y; acc[1][2] += f1 * wv.z; acc[1][3] += f1 * wv.w;
            }
        }
#pragma unroll
        for (int j = 0; j < 2; j++) {
            int node = base + ty * 2 + j;
            if (node < N) {
                float4* p = (float4*)&h[(size_t)node * HDIM + 4 * tx];
                float4 old = *p;
                float4 nv = make_float4(old.x + acc[j][0], old.y + acc[j][1],
                                        old.z + acc[j][2], old.w + acc[j][3]);
                *p = nv;
                s0 += nv.x; q0 += nv.x * nv.x;
                s1 += nv.y; q1 += nv.y * nv.y;
                s2 += nv.z; q2 += nv.z * nv.z;
                s3 += nv.w; q3 += nv.w * nv.w;
            }
        }
    }
    float sq[8] = { s0, s1, s2, s3, q0, q1, q2, q3 };
#pragma unroll
    for (int q = 0; q < 8; q++) {
        __syncthreads();
        red[tid] = sq[q];
        __syncthreads();
        if (tid < 16) {
            float t = 0.f;
#pragma unroll
            for (int k = 0; k < 16; k++) t += red[tid + 16 * k];
            atomicAdd(&nstats[(q < 4 ? 0 : 64) + 4 * tid + (q & 3)], t);
        }
    }
}

// ---------------------------------------------------------------- pool + head
__global__ __launch_bounds__(1024) void pool_out_kernel(
        const float* __restrict__ h, const int* __restrict__ gstart,
        const float* __restrict__ Wo, const float* __restrict__ bo,
        float* __restrict__ out, int N) {
    __shared__ float sp[HDIM];
    __shared__ float red[1024];
    __shared__ float sW[HDIM * COUT];
    int g = blockIdx.x;
    int tid = threadIdx.x;
    for (int i = tid; i < HDIM * COUT; i += 1024) sW[i] = Wo[i];
    int beg = gstart[g], end = gstart[g + 1];
    int c = tid & 63, r0 = tid >> 6;
    float s = 0.f;
    for (int r = beg + r0; r < end; r += 16) s += h[(size_t)r * HDIM + c];
    red[tid] = s;
    __syncthreads();
    if (tid < HDIM) {
        s = 0.f;
#pragma unroll
        for (int k = 0; k < 16; k++) s += red[tid + 64 * k];
        float cnt = (float)(end - beg);
        float pooled = s / fmaxf(cnt, 1.0f);
        sp[tid] = fmaxf(pooled, 0.0f);
    }
    __syncthreads();
    if (tid < COUT) {
        float acc = bo[tid];
#pragma unroll
        for (int k = 0; k < HDIM; k++) acc += sp[k] * sW[k * COUT + tid];
        out[g * COUT + tid] = acc;
    }
}

// ================================================================ launch
extern "C" void kernel_launch(void* const* d_in, const int* in_sizes, int n_in,
                              void* d_out, int out_size, void* d_ws, size_t ws_size,
                              hipStream_t stream) {
    (void)in_sizes; (void)n_in; (void)out_size;
    const float* x          = (const float*)d_in[0];
    const int*   eidx       = (const int*)  d_in[1];
    const float* eattr      = (const float*)d_in[2];
    const int*   batch      = (const int*)  d_in[3];
    const float* lin_in_w   = (const float*)d_in[4];
    const float* lin_in_b   = (const float*)d_in[5];
    const float* norm_gamma = (const float*)d_in[6];
    const float* norm_beta  = (const float*)d_in[7];
    const float* edge_w     = (const float*)d_in[8];
    const float* edge_b     = (const float*)d_in[9];
    const float* tparam     = (const float*)d_in[10];
    const float* mlp_w1     = (const float*)d_in[11];
    const float* mlp_b1     = (const float*)d_in[12];
    const float* mlp_gamma  = (const float*)d_in[13];
    const float* mlp_beta   = (const float*)d_in[14];
    const float* mlp_w2     = (const float*)d_in[15];
    const float* mlp_b2     = (const float*)d_in[16];
    const float* lin_out_w  = (const float*)d_in[17];
    const float* lin_out_b  = (const float*)d_in[18];
    float* out = (float*)d_out;

    const int* src = eidx;
    const int* dst = eidx + N_EDGES;

    char* ws = (char*)d_ws;
    size_t off = 0;
    auto alloc = [&](size_t bytes) -> char* {
        char* p = ws + off;
        off = (off + bytes + 255) & ~(size_t)255;
        return p;
    };
    // zero-init region first: histogram + all BN stat accumulators
    int*   cnt     = (int*)  alloc((size_t)N_NODES * 4);
    float* statsA0 = (float*)alloc(128 * 4);
    float* statsB0 = (float*)alloc(256 * 4);
    float* statsA1 = (float*)alloc(128 * 4);
    float* statsB1 = (float*)alloc(256 * 4);
    float* statsA2 = (float*)alloc(128 * 4);
    size_t zero_bytes = off;
    int*   bsum    = (int*)  alloc(256 * 4);
    int*   offsets = (int*)  alloc((size_t)(N_NODES + 1) * 4);
    int*   cursor  = (int*)  alloc((size_t)N_NODES * 4);
    int*   pos     = (int*)  alloc((size_t)N_EDGES * 4);
    int*   sorted  = (int*)  alloc((size_t)N_EDGES * 4);
    int*   gstart  = (int*)  alloc((size_t)(NGRAPH + 1) * 4);
    float* h       = (float*)alloc((size_t)N_NODES * HDIM * 4);
    float* ob      = (float*)alloc((size_t)N_NODES * HDIM * 4);
    float* h1      = (float*)alloc((size_t)N_NODES * 2 * HDIM * 4);
    // fast-path buffers (54.4 MB): edge data permuted into dst-sorted order
    size_t need_fast = off + (size_t)N_EDGES * 4 + 256 + (size_t)N_EDGES * EDIM * 4 + 256;
    bool fast = (ws_size >= need_fast);
    int*   src_sorted = nullptr;
    float* ea_sorted  = nullptr;
    if (fast) {
        src_sorted = (int*)  alloc((size_t)N_EDGES * 4);
        ea_sorted  = (float*)alloc((size_t)N_EDGES * EDIM * 4);
    }

    hipMemsetAsync(d_ws, 0, zero_bytes, stream);

    const int NB = (N_NODES + 255) / 256;
    hist_kernel      <<<(N_EDGES + 255) / 256, 256, 0, stream>>>(dst, cnt, N_EDGES);
    scan_part_kernel <<<NB, 256, 0, stream>>>(cnt, bsum, N_NODES);
    scan_top_kernel  <<<1, 256, 0, stream>>>(bsum, NB);
    scan_apply_kernel<<<NB, 256, 0, stream>>>(cnt, bsum, offsets, cursor, N_NODES);
    scatter_kernel   <<<(N_EDGES + 255) / 256, 256, 0, stream>>>(dst, cursor, pos, sorted, N_EDGES);
    if (fast)
        permute_kernel<<<(N_EDGES + 255) / 256, 256, 0, stream>>>(
            pos, src, (const float4*)eattr, (float4*)ea_sorted, src_sorted, N_EDGES);
    gstart_kernel    <<<NB, 256, 0, stream>>>(batch, gstart, N_NODES, NGRAPH);
    lin_in_kernel    <<<256, 256, 0, stream>>>(x, lin_in_w, lin_in_b, h, statsA0, N_NODES);

    float* statsA[3] = { statsA0, statsA1, statsA2 };
    float* statsB[2] = { statsB0, statsB1 };
    const int NTILES = (N_NODES + 31) / 32;   // 1563, one tile per block
    for (int l = 0; l < 2; l++) {
        agg_kernel<<<(N_NODES + 3) / 4, 256, 0, stream>>>(
            h,
            fast ? src_sorted : src,
            fast ? ea_sorted : eattr,
            edge_w + (size_t)l * EDIM * HDIM, edge_b + l * HDIM,
            tparam + l, statsA[l], norm_gamma + l * HDIM, norm_beta + l * HDIM,
            offsets, fast ? nullptr : sorted, ob, N_NODES);
        mlp1_kernel<<<NTILES, 256, 0, stream>>>(
            ob, mlp_w1 + (size_t)l * HDIM * 2 * HDIM, mlp_b1 + l * 2 * HDIM,
            h1, statsB[l], N_NODES);
        mlp2_kernel<<<NTILES, 256, 0, stream>>>(
            h1, statsB[l], mlp_gamma + l * 2 * HDIM, mlp_beta + l * 2 * HDIM,
            mlp_w2 + (size_t)l * 2 * HDIM * HDIM, mlp_b2 + l * HDIM,
            h, statsA[l + 1], N_NODES);
    }
    pool_out_kernel<<<NGRAPH, 1024, 0, stream>>>(h, gstart, lin_out_w, lin_out_b, out, N_NODES);
}

// Round 8
// 1063.445 us; speedup vs baseline: 1.1148x; 1.1148x over previous
//
#include <hip/hip_runtime.h>

#define N_NODES 50000
#define N_EDGES 800000
#define F_INP   32
#define HDIM    64
#define EDIM    16
#define COUT    40
#define NGRAPH  64

// ---------------------------------------------------------------- sort by dst
__global__ void hist_kernel(const int* __restrict__ dst, int* __restrict__ cnt, int E) {
    int e = blockIdx.x * 256 + threadIdx.x;
    if (e < E) atomicAdd(&cnt[dst[e]], 1);
}

__global__ void scan_part_kernel(const int* __restrict__ cnt, int* __restrict__ bsum, int n) {
    __shared__ int red[256];
    int tid = threadIdx.x;
    int idx = blockIdx.x * 256 + tid;
    red[tid] = (idx < n) ? cnt[idx] : 0;
    __syncthreads();
    for (int off = 128; off > 0; off >>= 1) {
        if (tid < off) red[tid] += red[tid + off];
        __syncthreads();
    }
    if (tid == 0) bsum[blockIdx.x] = red[0];
}

__global__ void scan_top_kernel(int* __restrict__ bsum, int nb) {
    __shared__ int tmp[256];
    int tid = threadIdx.x;
    int v = (tid < nb) ? bsum[tid] : 0;
    tmp[tid] = v;
    __syncthreads();
    for (int off = 1; off < 256; off <<= 1) {
        int x = (tid >= off) ? tmp[tid - off] : 0;
        __syncthreads();
        tmp[tid] += x;
        __syncthreads();
    }
    if (tid < nb) bsum[tid] = tmp[tid] - v;   // exclusive
}

__global__ void scan_apply_kernel(const int* __restrict__ cnt, const int* __restrict__ bsum,
                                  int* __restrict__ offsets, int* __restrict__ cursor, int n) {
    __shared__ int tmp[256];
    int tid = threadIdx.x;
    int idx = blockIdx.x * 256 + tid;
    int v = (idx < n) ? cnt[idx] : 0;
    tmp[tid] = v;
    __syncthreads();
    for (int off = 1; off < 256; off <<= 1) {
        int x = (tid >= off) ? tmp[tid - off] : 0;
        __syncthreads();
        tmp[tid] += x;
        __syncthreads();
    }
    int excl = tmp[tid] - v + bsum[blockIdx.x];
    if (idx < n) { offsets[idx] = excl; cursor[idx] = excl; }
    if (idx == n - 1) offsets[n] = excl + v;
}

__global__ void scatter_kernel(const int* __restrict__ dst, int* __restrict__ cursor,
                               int* __restrict__ pos, int* __restrict__ sorted, int E) {
    int e = blockIdx.x * 256 + threadIdx.x;
    if (e < E) {
        int p = atomicAdd(&cursor[dst[e]], 1);
        pos[e] = p;
        sorted[p] = e;
    }
}

// coalesced-read / scattered-write permute
__global__ void permute_kernel(const int* __restrict__ pos, const int* __restrict__ src,
                               const float4* __restrict__ ea, float4* __restrict__ ea_s,
                               int* __restrict__ src_s, int E) {
    int e = blockIdx.x * 256 + threadIdx.x;
    if (e >= E) return;
    int p = pos[e];
    float4 a0 = ea[e * 4 + 0], a1 = ea[e * 4 + 1];
    float4 a2 = ea[e * 4 + 2], a3 = ea[e * 4 + 3];
    ea_s[p * 4 + 0] = a0; ea_s[p * 4 + 1] = a1;
    ea_s[p * 4 + 2] = a2; ea_s[p * 4 + 3] = a3;
    src_s[p] = src[e];
}

__global__ void gstart_kernel(const int* __restrict__ batch, int* __restrict__ gstart,
                              int N, int G) {
    int n = blockIdx.x * 256 + threadIdx.x;
    if (n >= N) return;
    int g  = batch[n];
    int gp = (n == 0) ? -1 : batch[n - 1];
    for (int gg = gp + 1; gg <= g; gg++) gstart[gg] = n;
    if (n == N - 1) {
        for (int gg = g + 1; gg <= G; gg++) gstart[gg] = N;
    }
}

// ---------------------------------------------------------------- input linear
__global__ void lin_in_kernel(const float* __restrict__ x, const float* __restrict__ W,
                              const float* __restrict__ b, float* __restrict__ h,
                              float* __restrict__ nstats, int N) {
    __shared__ float red[256];
    int tid = threadIdx.x;
    int c = tid & 63;
    float w[F_INP];
#pragma unroll
    for (int k = 0; k < F_INP; k++) w[k] = W[k * HDIM + c];
    float bc = b[c];
    float s = 0.f, ss = 0.f;
    for (int node = blockIdx.x * 4 + (tid >> 6); node < N; node += gridDim.x * 4) {
        const float4* xr = (const float4*)(x + (size_t)node * F_INP);
        float acc = bc;
#pragma unroll
        for (int k4 = 0; k4 < F_INP / 4; k4++) {
            float4 xv = xr[k4];
            acc += xv.x * w[4 * k4] + xv.y * w[4 * k4 + 1]
                 + xv.z * w[4 * k4 + 2] + xv.w * w[4 * k4 + 3];
        }
        h[(size_t)node * HDIM + c] = acc;
        s += acc; ss += acc * acc;
    }
    __syncthreads();
    red[tid] = s;
    __syncthreads();
    if (tid < 64) atomicAdd(&nstats[tid], red[tid] + red[tid + 64] + red[tid + 128] + red[tid + 192]);
    __syncthreads();
    red[tid] = ss;
    __syncthreads();
    if (tid < 64) atomicAdd(&nstats[64 + tid], red[tid] + red[tid + 64] + red[tid + 128] + red[tid + 192]);
}

// ---------------------------------------------------------------- aggregation
// (R6 form — known 122 us) one wave per node; BN fused; 1-deep h[src] prefetch
__global__ void agg_kernel(const float* __restrict__ h, const int* __restrict__ srcarr,
                           const float* __restrict__ ea, const float* __restrict__ We,
                           const float* __restrict__ be, const float* __restrict__ tptr,
                           const float* __restrict__ stats,
                           const float* __restrict__ gamma, const float* __restrict__ beta,
                           const int* __restrict__ offsets, const int* __restrict__ sorted,
                           float* __restrict__ out, int N) {
    int tid = threadIdx.x;
    int c = tid & 63;
    float inv = 1.0f / (float)N;
    float mu  = stats[c] * inv;
    float var = stats[HDIM + c] * inv - mu * mu;
    float rs  = rsqrtf(var + 1e-5f);
    float A   = rs * gamma[c];
    float B   = beta[c] - mu * A;
    float w[EDIM];
#pragma unroll
    for (int k = 0; k < EDIM; k++) w[k] = We[k * HDIM + c];
    float bc = be[c];
    float tval = *tptr;
    int node = blockIdx.x * 4 + (tid >> 6);
    if (node >= N) return;
    int beg = offsets[node], end = offsets[node + 1];
    float denom = 0.f, num = 0.f;
    if (sorted == nullptr) {
        for (int cb = beg; cb < end; cb += 64) {
            int nc = end - cb; if (nc > 64) nc = 64;
            int s_l = 0;
            if (c < nc) s_l = srcarr[cb + c];
            int s0 = __shfl(s_l, 0);
            float hv_n = h[(size_t)s0 * HDIM + c];
            const float4* ar = (const float4*)(ea + (size_t)cb * EDIM);
            for (int j = 0; j < nc; j++) {
                float hv = hv_n;
                int jn = (j + 1 < nc) ? j + 1 : j;
                int sn = __shfl(s_l, jn);
                hv_n = h[(size_t)sn * HDIM + c];
                float4 a0 = ar[0], a1 = ar[1], a2 = ar[2], a3 = ar[3];
                ar += 4;
                float acc = bc
                    + a0.x * w[0]  + a0.y * w[1]  + a0.z * w[2]  + a0.w * w[3]
                    + a1.x * w[4]  + a1.y * w[5]  + a1.z * w[6]  + a1.w * w[7]
                    + a2.x * w[8]  + a2.y * w[9]  + a2.z * w[10] + a2.w * w[11]
                    + a3.x * w[12] + a3.y * w[13] + a3.z * w[14] + a3.w * w[15];
                float zv = fmaxf(hv * A + B, 0.f);
                float m  = fmaxf(zv + acc, 0.f) + 1e-7f;
                float ex = __expf(m * tval);
                denom += ex;
                num   += ex * m;
            }
        }
    } else {
        for (int cb = beg; cb < end; cb += 64) {
            int nc = end - cb; if (nc > 64) nc = 64;
            int e_l = 0, s_l = 0;
            if (c < nc) { e_l = sorted[cb + c]; s_l = srcarr[e_l]; }
            for (int j = 0; j < nc; j++) {
                int e = __shfl(e_l, j);
                int s = __shfl(s_l, j);
                const float4* ar = (const float4*)(ea + (size_t)e * EDIM);
                float4 a0 = ar[0], a1 = ar[1], a2 = ar[2], a3 = ar[3];
                float acc = bc
                    + a0.x * w[0]  + a0.y * w[1]  + a0.z * w[2]  + a0.w * w[3]
                    + a1.x * w[4]  + a1.y * w[5]  + a1.z * w[6]  + a1.w * w[7]
                    + a2.x * w[8]  + a2.y * w[9]  + a2.z * w[10] + a2.w * w[11]
                    + a3.x * w[12] + a3.y * w[13] + a3.z * w[14] + a3.w * w[15];
                float hv = h[(size_t)s * HDIM + c];
                float zv = fmaxf(hv * A + B, 0.f);
                float m  = fmaxf(zv + acc, 0.f) + 1e-7f;
                float ex = __expf(m * tval);
                denom += ex;
                num   += ex * m;
            }
        }
    }
    float hv = h[(size_t)node * HDIM + c];
    float zn = fmaxf(hv * A + B, 0.f);
    out[(size_t)node * HDIM + c] = num / (denom + 1e-16f) + zn;
}

// ---------------------------------------------------------------- MLP part 1
// h1 = in @ W1 + b1  (N,64)@(64,128). Weight-stationary: lane = output o,
// w[64] in VGPRs; input rows via broadcast float4; no LDS in hot loop.
__global__ void mlp1_kernel(const float* __restrict__ in, const float* __restrict__ W1,
                            const float* __restrict__ b1, float* __restrict__ h1,
                            float* __restrict__ stats, int N) {
    __shared__ float red[256];
    int tid = threadIdx.x;
    int o = tid & 127;                       // output channel
    int nodesel = tid >> 7;                  // 0..1
    float w[HDIM];
#pragma unroll
    for (int k = 0; k < HDIM; k++) w[k] = W1[k * 128 + o];
    float bo = b1[o];
    float s = 0.f, ss = 0.f;
    for (int base = blockIdx.x * 2; base < N; base += gridDim.x * 2) {
        int node = base + nodesel;
        if (node < N) {
            const float4* xr = (const float4*)(in + (size_t)node * HDIM);
            float acc = bo;
#pragma unroll
            for (int k4 = 0; k4 < HDIM / 4; k4++) {
                float4 xv = xr[k4];
                acc += xv.x * w[4 * k4] + xv.y * w[4 * k4 + 1]
                     + xv.z * w[4 * k4 + 2] + xv.w * w[4 * k4 + 3];
            }
            h1[(size_t)node * 128 + o] = acc;
            s += acc; ss += acc * acc;
        }
    }
    __syncthreads();
    red[tid] = s;
    __syncthreads();
    if (tid < 128) atomicAdd(&stats[tid], red[tid] + red[tid + 128]);
    __syncthreads();
    red[tid] = ss;
    __syncthreads();
    if (tid < 128) atomicAdd(&stats[128 + tid], red[tid] + red[tid + 128]);
}

// precompute BN scale/shift for h1: A = rs*gamma, B = beta - mu*A
__global__ void bnprep_kernel(const float* __restrict__ stats, const float* __restrict__ mg,
                              const float* __restrict__ mb, float* __restrict__ bnAB, int N) {
    int o = threadIdx.x;                     // 128 threads
    float inv = 1.0f / (float)N;
    float mu  = stats[o] * inv;
    float var = stats[128 + o] * inv - mu * mu;
    float A   = rsqrtf(var + 1e-5f) * mg[o];
    bnAB[o]       = A;
    bnAB[128 + o] = mb[o] - mu * A;
}

// in-place h1 = relu(h1*A + B), float4 grid-stride
__global__ void bnact_kernel(float* __restrict__ h1, const float* __restrict__ bnAB, int n4) {
    const float4* A4 = (const float4*)bnAB;
    const float4* B4 = (const float4*)(bnAB + 128);
    for (int i = blockIdx.x * 256 + threadIdx.x; i < n4; i += gridDim.x * 256) {
        int o4 = i & 31;                     // 32 float4 per 128-row
        float4 v = ((float4*)h1)[i];
        float4 a = A4[o4], b = B4[o4];
        v.x = fmaxf(v.x * a.x + b.x, 0.f);
        v.y = fmaxf(v.y * a.y + b.y, 0.f);
        v.z = fmaxf(v.z * a.z + b.z, 0.f);
        v.w = fmaxf(v.w * a.w + b.w, 0.f);
        ((float4*)h1)[i] = v;
    }
}

// ---------------------------------------------------------------- MLP part 2
// h += act @ W2 + b2  (N,128)@(128,64). Lane = output c, w[128] in VGPRs
// (statically indexed, ~150 VGPR, no spill); broadcast float4 act reads.
// Epilogue: stats of NEW h.
__global__ void mlp2_kernel(const float* __restrict__ act, const float* __restrict__ W2,
                            const float* __restrict__ b2, float* __restrict__ h,
                            float* __restrict__ nstats, int N) {
    __shared__ float red[256];
    int tid = threadIdx.x;
    int c = tid & 63;
    int nodesel = tid >> 6;                  // 0..3
    float w[2 * HDIM];
#pragma unroll
    for (int k = 0; k < 2 * HDIM; k++) w[k] = W2[k * HDIM + c];
    float bc = b2[c];
    float s = 0.f, ss = 0.f;
    for (int base = blockIdx.x * 4; base < N; base += gridDim.x * 4) {
        int node = base + nodesel;
        if (node < N) {
            const float4* xr = (const float4*)(act + (size_t)node * 128);
            float acc = bc;
#pragma unroll
            for (int k4 = 0; k4 < 32; k4++) {
                float4 xv = xr[k4];
                acc += xv.x * w[4 * k4] + xv.y * w[4 * k4 + 1]
                     + xv.z * w[4 * k4 + 2] + xv.w * w[4 * k4 + 3];
            }
            float hn = h[(size_t)node * HDIM + c] + acc;
            h[(size_t)node * HDIM + c] = hn;
            s += hn; ss += hn * hn;
        }
    }
    __syncthreads();
    red[tid] = s;
    __syncthreads();
    if (tid < 64) atomicAdd(&nstats[tid], red[tid] + red[tid + 64] + red[tid + 128] + red[tid + 192]);
    __syncthreads();
    red[tid] = ss;
    __syncthreads();
    if (tid < 64) atomicAdd(&nstats[64 + tid], red[tid] + red[tid + 64] + red[tid + 128] + red[tid + 192]);
}

// ---------------------------------------------------------------- pool + head
__global__ __launch_bounds__(1024) void pool_out_kernel(
        const float* __restrict__ h, const int* __restrict__ gstart,
        const float* __restrict__ Wo, const float* __restrict__ bo,
        float* __restrict__ out, int N) {
    __shared__ float sp[HDIM];
    __shared__ float red[1024];
    __shared__ float sW[HDIM * COUT];
    int g = blockIdx.x;
    int tid = threadIdx.x;
    for (int i = tid; i < HDIM * COUT; i += 1024) sW[i] = Wo[i];
    int beg = gstart[g], end = gstart[g + 1];
    int c = tid & 63, r0 = tid >> 6;
    float s = 0.f;
    for (int r = beg + r0; r < end; r += 16) s += h[(size_t)r * HDIM + c];
    red[tid] = s;
    __syncthreads();
    if (tid < HDIM) {
        s = 0.f;
#pragma unroll
        for (int k = 0; k < 16; k++) s += red[tid + 64 * k];
        float cnt = (float)(end - beg);
        float pooled = s / fmaxf(cnt, 1.0f);
        sp[tid] = fmaxf(pooled, 0.0f);
    }
    __syncthreads();
    if (tid < COUT) {
        float acc = bo[tid];
#pragma unroll
        for (int k = 0; k < HDIM; k++) acc += sp[k] * sW[k * COUT + tid];
        out[g * COUT + tid] = acc;
    }
}

// ================================================================ launch
extern "C" void kernel_launch(void* const* d_in, const int* in_sizes, int n_in,
                              void* d_out, int out_size, void* d_ws, size_t ws_size,
                              hipStream_t stream) {
    (void)in_sizes; (void)n_in; (void)out_size;
    const float* x          = (const float*)d_in[0];
    const int*   eidx       = (const int*)  d_in[1];
    const float* eattr      = (const float*)d_in[2];
    const int*   batch      = (const int*)  d_in[3];
    const float* lin_in_w   = (const float*)d_in[4];
    const float* lin_in_b   = (const float*)d_in[5];
    const float* norm_gamma = (const float*)d_in[6];
    const float* norm_beta  = (const float*)d_in[7];
    const float* edge_w     = (const float*)d_in[8];
    const float* edge_b     = (const float*)d_in[9];
    const float* tparam     = (const float*)d_in[10];
    const float* mlp_w1     = (const float*)d_in[11];
    const float* mlp_b1     = (const float*)d_in[12];
    const float* mlp_gamma  = (const float*)d_in[13];
    const float* mlp_beta   = (const float*)d_in[14];
    const float* mlp_w2     = (const float*)d_in[15];
    const float* mlp_b2     = (const float*)d_in[16];
    const float* lin_out_w  = (const float*)d_in[17];
    const float* lin_out_b  = (const float*)d_in[18];
    float* out = (float*)d_out;

    const int* src = eidx;
    const int* dst = eidx + N_EDGES;

    char* ws = (char*)d_ws;
    size_t off = 0;
    auto alloc = [&](size_t bytes) -> char* {
        char* p = ws + off;
        off = (off + bytes + 255) & ~(size_t)255;
        return p;
    };
    // zero-init region: histogram + BN stat accumulators
    int*   cnt     = (int*)  alloc((size_t)N_NODES * 4);
    float* statsA0 = (float*)alloc(128 * 4);
    float* statsB0 = (float*)alloc(256 * 4);
    float* statsA1 = (float*)alloc(128 * 4);
    float* statsB1 = (float*)alloc(256 * 4);
    float* statsA2 = (float*)alloc(128 * 4);
    size_t zero_bytes = off;
    int*   bsum    = (int*)  alloc(256 * 4);
    int*   offsets = (int*)  alloc((size_t)(N_NODES + 1) * 4);
    int*   cursor  = (int*)  alloc((size_t)N_NODES * 4);
    int*   pos     = (int*)  alloc((size_t)N_EDGES * 4);
    int*   sorted  = (int*)  alloc((size_t)N_EDGES * 4);
    int*   gstart  = (int*)  alloc((size_t)(NGRAPH + 1) * 4);
    float* bnAB    = (float*)alloc(256 * 4);
    float* h       = (float*)alloc((size_t)N_NODES * HDIM * 4);
    float* ob      = (float*)alloc((size_t)N_NODES * HDIM * 4);
    float* h1      = (float*)alloc((size_t)N_NODES * 2 * HDIM * 4);
    // fast-path buffers: edge data permuted into dst-sorted order
    size_t need_fast = off + (size_t)N_EDGES * 4 + 256 + (size_t)N_EDGES * EDIM * 4 + 256;
    bool fast = (ws_size >= need_fast);
    int*   src_sorted = nullptr;
    float* ea_sorted  = nullptr;
    if (fast) {
        src_sorted = (int*)  alloc((size_t)N_EDGES * 4);
        ea_sorted  = (float*)alloc((size_t)N_EDGES * EDIM * 4);
    }

    hipMemsetAsync(d_ws, 0, zero_bytes, stream);

    const int NB = (N_NODES + 255) / 256;
    hist_kernel      <<<(N_EDGES + 255) / 256, 256, 0, stream>>>(dst, cnt, N_EDGES);
    scan_part_kernel <<<NB, 256, 0, stream>>>(cnt, bsum, N_NODES);
    scan_top_kernel  <<<1, 256, 0, stream>>>(bsum, NB);
    scan_apply_kernel<<<NB, 256, 0, stream>>>(cnt, bsum, offsets, cursor, N_NODES);
    scatter_kernel   <<<(N_EDGES + 255) / 256, 256, 0, stream>>>(dst, cursor, pos, sorted, N_EDGES);
    if (fast)
        permute_kernel<<<(N_EDGES + 255) / 256, 256, 0, stream>>>(
            pos, src, (const float4*)eattr, (float4*)ea_sorted, src_sorted, N_EDGES);
    gstart_kernel    <<<NB, 256, 0, stream>>>(batch, gstart, N_NODES, NGRAPH);
    lin_in_kernel    <<<256, 256, 0, stream>>>(x, lin_in_w, lin_in_b, h, statsA0, N_NODES);

    float* statsA[3] = { statsA0, statsA1, statsA2 };
    float* statsB[2] = { statsB0, statsB1 };
    for (int l = 0; l < 2; l++) {
        agg_kernel<<<(N_NODES + 3) / 4, 256, 0, stream>>>(
            h,
            fast ? src_sorted : src,
            fast ? ea_sorted : eattr,
            edge_w + (size_t)l * EDIM * HDIM, edge_b + l * HDIM,
            tparam + l, statsA[l], norm_gamma + l * HDIM, norm_beta + l * HDIM,
            offsets, fast ? nullptr : sorted, ob, N_NODES);
        mlp1_kernel<<<512, 256, 0, stream>>>(
            ob, mlp_w1 + (size_t)l * HDIM * 2 * HDIM, mlp_b1 + l * 2 * HDIM,
            h1, statsB[l], N_NODES);
        bnprep_kernel<<<1, 128, 0, stream>>>(
            statsB[l], mlp_gamma + l * 2 * HDIM, mlp_beta + l * 2 * HDIM, bnAB, N_NODES);
        bnact_kernel<<<512, 256, 0, stream>>>(h1, bnAB, N_NODES * 128 / 4);
        mlp2_kernel<<<512, 256, 0, stream>>>(
            h1, mlp_w2 + (size_t)l * 2 * HDIM * HDIM, mlp_b2 + l * HDIM,
            h, statsA[l + 1], N_NODES);
    }
    pool_out_kernel<<<NGRAPH, 1024, 0, stream>>>(h, gstart, lin_out_w, lin_out_b, out, N_NODES);
}